// Round 8
// baseline (451.732 us; speedup 1.0000x reference)
//
#include <hip/hip_runtime.h>
#include <hip/hip_fp16.h>
#include <math.h>

#define N_NODES    1000000
#define N_EDGES    16000000
#define NUM_GRAPHS 64
#define LATENT     128

// ws layout (doubles):
// [0..4): legacy scalars: [1] S1 [2] S2 (legacy edge mode)
// node shadow region: 8 copies at SH_BASE + s*SH_STRIDE:
//   +0 recon, +1 kl, +2..66 gx, +66..130 gy, +130..194 cnt
// edge shadows (big mode): 16 line-separated {S1,S2} pairs at EDGE_SH_BASE + sh*8
// packed half2 table at byte offset 16384 (big mode) or 2048 (legacy mode)
#define SH_BASE        8
#define SH_STRIDE      200
#define NSHADOW_BIG    8
#define EDGE_SH_BASE   1608   // 8 + 8*200
#define EDGE_NSHADOW   16
#define WS_DOUBLES_TOT 1736   // 1608 + 16*8
#define WS_DOUBLES_LEGACY 208
#define PACKED_OFFSET_BIG    16384
#define PACKED_OFFSET_LEGACY 2048

typedef int vint4 __attribute__((ext_vector_type(4)));

__global__ void init_ws(double* ws, int n) {
    int t = blockIdx.x * blockDim.x + threadIdx.x;
    if (t < n) ws[t] = 0.0;
}

__global__ void node_kl_pass(const float2* __restrict__ pred,
                             const float2* __restrict__ targ,
                             const int*    __restrict__ batch,
                             const float*  __restrict__ mu,
                             const float*  __restrict__ logvar,
                             double* __restrict__ ws,
                             unsigned* __restrict__ packed,  // may be null
                             int ns) {
    __shared__ float sgx[NUM_GRAPHS];
    __shared__ float sgy[NUM_GRAPHS];
    __shared__ int   scnt[NUM_GRAPHS];
    __shared__ double smem[8];

    for (int g = threadIdx.x; g < NUM_GRAPHS; g += blockDim.x) {
        sgx[g] = 0.f; sgy[g] = 0.f; scnt[g] = 0;
    }
    __syncthreads();

    double* shbase = ws + SH_BASE + (size_t)(blockIdx.x & (ns - 1)) * SH_STRIDE;

    float recon = 0.f;
    const int idx = blockIdx.x * blockDim.x + threadIdx.x;
    const int stride = gridDim.x * blockDim.x;
    for (int n = idx; n < N_NODES; n += stride) {
        float2 p = pred[n];
        float2 t = targ[n];
        float dx = p.x - t.x, dy = p.y - t.y;
        recon += dx * dx + dy * dy;

        if (packed) {
            __half2 h = __floats2half2_rn(p.x, p.y);
            packed[n] = *reinterpret_cast<unsigned*>(&h);
        }

        int b = batch[n];
        // batch is sorted: waves are almost always graph-uniform.
        unsigned long long act = __ballot(1);
        int b0 = __shfl(b, 0);
        bool fast = (act == ~0ull) && (__ballot(b == b0) == act);
        if (fast) {
            float sx = p.x, sy = p.y;
            #pragma unroll
            for (int off = 32; off > 0; off >>= 1) {
                sx += __shfl_xor(sx, off);
                sy += __shfl_xor(sy, off);
            }
            if ((threadIdx.x & 63) == 0) {
                atomicAdd(&sgx[b0], sx);
                atomicAdd(&sgy[b0], sy);
                atomicAdd(&scnt[b0], 64);
            }
        } else {
            atomicAdd(&sgx[b], p.x);
            atomicAdd(&sgy[b], p.y);
            atomicAdd(&scnt[b], 1);
        }
    }

    // reduce recon across block
    double r = (double)recon;
    #pragma unroll
    for (int off = 32; off > 0; off >>= 1) r += __shfl_down(r, off);
    const int lane = threadIdx.x & 63;
    const int wid  = threadIdx.x >> 6;
    if (lane == 0) smem[wid] = r;
    __syncthreads();
    if (threadIdx.x == 0) {
        double tot = 0.0;
        const int nw = blockDim.x >> 6;
        for (int w = 0; w < nw; ++w) tot += smem[w];
        atomicAdd(&shbase[0], tot);
    }

    for (int g = threadIdx.x; g < NUM_GRAPHS; g += blockDim.x) {
        if (scnt[g] != 0) {
            atomicAdd(&shbase[2 + g],   (double)sgx[g]);
            atomicAdd(&shbase[66 + g],  (double)sgy[g]);
            atomicAdd(&shbase[130 + g], (double)scnt[g]);
        }
    }

    // KL tail: block 0 only (8192 elements, trivial)
    if (blockIdx.x == 0) {
        double s = 0.0;
        for (int t = threadIdx.x; t < NUM_GRAPHS * LATENT; t += blockDim.x) {
            float m = mu[t], lv = logvar[t];
            s += (double)(1.0f + lv - m * m - expf(lv));
        }
        #pragma unroll
        for (int off = 32; off > 0; off >>= 1) s += __shfl_down(s, off);
        __syncthreads();
        if (lane == 0) smem[wid] = s;
        __syncthreads();
        if (threadIdx.x == 0) {
            double tot = 0.0;
            const int nw = blockDim.x >> 6;
            for (int w = 0; w < nw; ++w) tot += smem[w];
            atomicAdd(&shbase[1], tot);
        }
    }
}

__device__ __forceinline__ void edge_flush(float s1, float s2, double* ws,
                                           int edge_mode,
                                           double* smem1, double* smem2) {
    double r1 = (double)s1, r2 = (double)s2;
    #pragma unroll
    for (int off = 32; off > 0; off >>= 1) {
        r1 += __shfl_down(r1, off);
        r2 += __shfl_down(r2, off);
    }
    const int lane = threadIdx.x & 63;
    const int wid  = threadIdx.x >> 6;
    if (lane == 0) { smem1[wid] = r1; smem2[wid] = r2; }
    __syncthreads();
    if (threadIdx.x == 0) {
        double t1 = 0.0, t2 = 0.0;
        const int nw = blockDim.x >> 6;
        for (int w = 0; w < nw; ++w) { t1 += smem1[w]; t2 += smem2[w]; }
        if (edge_mode) {
            // 16 line-separated shadow pairs: avoids one-line atomic chains
            const int sh = blockIdx.x & (EDGE_NSHADOW - 1);
            atomicAdd(&ws[EDGE_SH_BASE + sh * 8 + 0], t1);
            atomicAdd(&ws[EDGE_SH_BASE + sh * 8 + 1], t2);
        } else {
            atomicAdd(&ws[1], t1);
            atomicAdd(&ws[2], t2);
        }
    }
}

// System-scope non-temporal 16B load: sc0+sc1+nt -> does not allocate in
// L1/L2, keeping L2 exclusively for the gather table. Caller MUST wait
// (explicit vmcnt asm) before reading the result.
__device__ __forceinline__ vint4 ld_stream_x4(const vint4* p) {
    vint4 r;
    asm volatile("global_load_dwordx4 %0, %1, off sc0 sc1 nt"
                 : "=v"(r) : "v"(p) : "memory");
    return r;
}

// 4B gather, hand-tracked (caller MUST s_waitcnt before reading result).
// SC0=true: sc0 flag -> no L1 allocate/fill, served at L2 where the packed
// table is resident. SC0=false: default policy (L1-allocating) control arm.
template<bool SC0>
__device__ __forceinline__ unsigned gth(const unsigned* base, int idx) {
    unsigned r;
    if constexpr (SC0)
        asm volatile("global_load_dword %0, %1, %2 sc0"
                     : "=v"(r) : "v"(idx * 4), "s"(base) : "memory");
    else
        asm volatile("global_load_dword %0, %1, %2"
                     : "=v"(r) : "v"(idx * 4), "s"(base) : "memory");
    return r;
}

__device__ __forceinline__ void acc_pair(unsigned pa, unsigned pb,
                                         float& s1, float& s2) {
    __half2 ha = *reinterpret_cast<__half2*>(&pa);
    __half2 hb = *reinterpret_cast<__half2*>(&pb);
    float2 fa = __half22float2(ha);
    float2 fb = __half22float2(hb);
    float dx = fa.x - fb.x, dy = fa.y - fb.y;
    float l2 = dx * dx + dy * dy;
    s2 += l2;
    s1 += sqrtf(l2);
}

// ===== factorial arm: 8 edges / 16 gathers in flight =====
// issue 16 gathers (oldest) -> 4 index prefetches (newest) -> vmcnt(4)
// (gathers done, prefetch in flight) -> consume -> vmcnt(0) at loop bottom.
template<bool SC0>
__global__ void edge_pass8(const unsigned* __restrict__ packed,
                           const int* __restrict__ ei,
                           double* __restrict__ ws,
                           int edge_mode, int g0, int ngroups) {
    __shared__ double smem1[8];
    __shared__ double smem2[8];

    float s1 = 0.f, s2 = 0.f;
    const int gid = blockIdx.x * blockDim.x + threadIdx.x;
    const int stride = gridDim.x * blockDim.x;
    const vint4* eia = (const vint4*)ei;
    const vint4* eib = (const vint4*)(ei + N_EDGES);

    int g = gid;
    if (g < ngroups) {
        vint4 a0 = ld_stream_x4(eia + 2 * (g0 + g));
        vint4 a1 = ld_stream_x4(eia + 2 * (g0 + g) + 1);
        vint4 b0 = ld_stream_x4(eib + 2 * (g0 + g));
        vint4 b1 = ld_stream_x4(eib + 2 * (g0 + g) + 1);
        asm volatile("s_waitcnt vmcnt(0)"
                     : "+v"(a0), "+v"(a1), "+v"(b0), "+v"(b1) :: "memory");
        __builtin_amdgcn_sched_barrier(0);
        while (true) {
            unsigned q0  = gth<SC0>(packed, a0.x), q1  = gth<SC0>(packed, b0.x);
            unsigned q2  = gth<SC0>(packed, a0.y), q3  = gth<SC0>(packed, b0.y);
            unsigned q4  = gth<SC0>(packed, a0.z), q5  = gth<SC0>(packed, b0.z);
            unsigned q6  = gth<SC0>(packed, a0.w), q7  = gth<SC0>(packed, b0.w);
            unsigned q8  = gth<SC0>(packed, a1.x), q9  = gth<SC0>(packed, b1.x);
            unsigned q10 = gth<SC0>(packed, a1.y), q11 = gth<SC0>(packed, b1.y);
            unsigned q12 = gth<SC0>(packed, a1.z), q13 = gth<SC0>(packed, b1.z);
            unsigned q14 = gth<SC0>(packed, a1.w), q15 = gth<SC0>(packed, b1.w);

            const int gn = g + stride;
            const bool more = gn < ngroups;
            const int gs = g0 + (more ? gn : g);
            vint4 A0 = ld_stream_x4(eia + 2 * gs);
            vint4 A1 = ld_stream_x4(eia + 2 * gs + 1);
            vint4 B0 = ld_stream_x4(eib + 2 * gs);
            vint4 B1 = ld_stream_x4(eib + 2 * gs + 1);

            asm volatile("s_waitcnt vmcnt(4)"
                         : "+v"(q0), "+v"(q1), "+v"(q2), "+v"(q3),
                           "+v"(q4), "+v"(q5), "+v"(q6), "+v"(q7),
                           "+v"(q8), "+v"(q9), "+v"(q10), "+v"(q11),
                           "+v"(q12), "+v"(q13), "+v"(q14), "+v"(q15)
                         :: "memory");
            __builtin_amdgcn_sched_barrier(0);

            acc_pair(q0, q1, s1, s2);
            acc_pair(q2, q3, s1, s2);
            acc_pair(q4, q5, s1, s2);
            acc_pair(q6, q7, s1, s2);
            acc_pair(q8, q9, s1, s2);
            acc_pair(q10, q11, s1, s2);
            acc_pair(q12, q13, s1, s2);
            acc_pair(q14, q15, s1, s2);

            if (!more) break;
            asm volatile("s_waitcnt vmcnt(0)"
                         : "+v"(A0), "+v"(A1), "+v"(B0), "+v"(B1) :: "memory");
            __builtin_amdgcn_sched_barrier(0);
            g = gn; a0 = A0; a1 = A1; b0 = B0; b1 = B1;
        }
    }
    asm volatile("s_waitcnt vmcnt(0)" ::: "memory");
    edge_flush(s1, s2, ws, edge_mode, smem1, smem2);
}

// ===== factorial arm: 16 edges / 32 gathers in flight =====
// issue 32 gathers (oldest) -> 8 index prefetches (newest) -> vmcnt(8)
// twice (16 result-ties each; second wait is a runtime no-op, just ties the
// remaining results) -> consume -> vmcnt(0) at loop bottom.
template<bool SC0>
__global__ void edge_pass16(const unsigned* __restrict__ packed,
                            const int* __restrict__ ei,
                            double* __restrict__ ws,
                            int edge_mode, int g0, int ngroups) {
    __shared__ double smem1[8];
    __shared__ double smem2[8];

    float s1 = 0.f, s2 = 0.f;
    const int gid = blockIdx.x * blockDim.x + threadIdx.x;
    const int stride = gridDim.x * blockDim.x;
    const vint4* eia = (const vint4*)ei;
    const vint4* eib = (const vint4*)(ei + N_EDGES);

    int g = gid;
    if (g < ngroups) {
        vint4 a0 = ld_stream_x4(eia + 4 * (g0 + g));
        vint4 a1 = ld_stream_x4(eia + 4 * (g0 + g) + 1);
        vint4 a2 = ld_stream_x4(eia + 4 * (g0 + g) + 2);
        vint4 a3 = ld_stream_x4(eia + 4 * (g0 + g) + 3);
        vint4 b0 = ld_stream_x4(eib + 4 * (g0 + g));
        vint4 b1 = ld_stream_x4(eib + 4 * (g0 + g) + 1);
        vint4 b2 = ld_stream_x4(eib + 4 * (g0 + g) + 2);
        vint4 b3 = ld_stream_x4(eib + 4 * (g0 + g) + 3);
        asm volatile("s_waitcnt vmcnt(0)"
                     : "+v"(a0), "+v"(a1), "+v"(a2), "+v"(a3),
                       "+v"(b0), "+v"(b1), "+v"(b2), "+v"(b3) :: "memory");
        __builtin_amdgcn_sched_barrier(0);
        while (true) {
            unsigned q0  = gth<SC0>(packed, a0.x), q1  = gth<SC0>(packed, b0.x);
            unsigned q2  = gth<SC0>(packed, a0.y), q3  = gth<SC0>(packed, b0.y);
            unsigned q4  = gth<SC0>(packed, a0.z), q5  = gth<SC0>(packed, b0.z);
            unsigned q6  = gth<SC0>(packed, a0.w), q7  = gth<SC0>(packed, b0.w);
            unsigned q8  = gth<SC0>(packed, a1.x), q9  = gth<SC0>(packed, b1.x);
            unsigned q10 = gth<SC0>(packed, a1.y), q11 = gth<SC0>(packed, b1.y);
            unsigned q12 = gth<SC0>(packed, a1.z), q13 = gth<SC0>(packed, b1.z);
            unsigned q14 = gth<SC0>(packed, a1.w), q15 = gth<SC0>(packed, b1.w);
            unsigned q16 = gth<SC0>(packed, a2.x), q17 = gth<SC0>(packed, b2.x);
            unsigned q18 = gth<SC0>(packed, a2.y), q19 = gth<SC0>(packed, b2.y);
            unsigned q20 = gth<SC0>(packed, a2.z), q21 = gth<SC0>(packed, b2.z);
            unsigned q22 = gth<SC0>(packed, a2.w), q23 = gth<SC0>(packed, b2.w);
            unsigned q24 = gth<SC0>(packed, a3.x), q25 = gth<SC0>(packed, b3.x);
            unsigned q26 = gth<SC0>(packed, a3.y), q27 = gth<SC0>(packed, b3.y);
            unsigned q28 = gth<SC0>(packed, a3.z), q29 = gth<SC0>(packed, b3.z);
            unsigned q30 = gth<SC0>(packed, a3.w), q31 = gth<SC0>(packed, b3.w);

            const int gn = g + stride;
            const bool more = gn < ngroups;
            const int gs = g0 + (more ? gn : g);
            vint4 A0 = ld_stream_x4(eia + 4 * gs);
            vint4 A1 = ld_stream_x4(eia + 4 * gs + 1);
            vint4 A2 = ld_stream_x4(eia + 4 * gs + 2);
            vint4 A3 = ld_stream_x4(eia + 4 * gs + 3);
            vint4 B0 = ld_stream_x4(eib + 4 * gs);
            vint4 B1 = ld_stream_x4(eib + 4 * gs + 1);
            vint4 B2 = ld_stream_x4(eib + 4 * gs + 2);
            vint4 B3 = ld_stream_x4(eib + 4 * gs + 3);

            // wait until only the 8 prefetches remain; split into two asm
            // statements (16 ties each) to stay under operand limits — the
            // second is a runtime no-op that ties the other 16 results.
            asm volatile("s_waitcnt vmcnt(8)"
                         : "+v"(q0), "+v"(q1), "+v"(q2), "+v"(q3),
                           "+v"(q4), "+v"(q5), "+v"(q6), "+v"(q7),
                           "+v"(q8), "+v"(q9), "+v"(q10), "+v"(q11),
                           "+v"(q12), "+v"(q13), "+v"(q14), "+v"(q15)
                         :: "memory");
            asm volatile("s_waitcnt vmcnt(8)"
                         : "+v"(q16), "+v"(q17), "+v"(q18), "+v"(q19),
                           "+v"(q20), "+v"(q21), "+v"(q22), "+v"(q23),
                           "+v"(q24), "+v"(q25), "+v"(q26), "+v"(q27),
                           "+v"(q28), "+v"(q29), "+v"(q30), "+v"(q31)
                         :: "memory");
            __builtin_amdgcn_sched_barrier(0);

            acc_pair(q0, q1, s1, s2);
            acc_pair(q2, q3, s1, s2);
            acc_pair(q4, q5, s1, s2);
            acc_pair(q6, q7, s1, s2);
            acc_pair(q8, q9, s1, s2);
            acc_pair(q10, q11, s1, s2);
            acc_pair(q12, q13, s1, s2);
            acc_pair(q14, q15, s1, s2);
            acc_pair(q16, q17, s1, s2);
            acc_pair(q18, q19, s1, s2);
            acc_pair(q20, q21, s1, s2);
            acc_pair(q22, q23, s1, s2);
            acc_pair(q24, q25, s1, s2);
            acc_pair(q26, q27, s1, s2);
            acc_pair(q28, q29, s1, s2);
            acc_pair(q30, q31, s1, s2);

            if (!more) break;
            asm volatile("s_waitcnt vmcnt(0)"
                         : "+v"(A0), "+v"(A1), "+v"(A2), "+v"(A3),
                           "+v"(B0), "+v"(B1), "+v"(B2), "+v"(B3) :: "memory");
            __builtin_amdgcn_sched_barrier(0);
            g = gn;
            a0 = A0; a1 = A1; a2 = A2; a3 = A3;
            b0 = B0; b1 = B1; b2 = B2; b3 = B3;
        }
    }
    asm volatile("s_waitcnt vmcnt(0)" ::: "memory");
    edge_flush(s1, s2, ws, edge_mode, smem1, smem2);
}

// Fallback (ws too small for packed table): original float2 gathers.
__global__ void edge_pass_f32(const float2* __restrict__ pred,
                              const int* __restrict__ ei,
                              double* __restrict__ ws,
                              int edge_mode) {
    __shared__ double smem1[8];
    __shared__ double smem2[8];

    float s1 = 0.f, s2 = 0.f;
    const int idx = blockIdx.x * blockDim.x + threadIdx.x;
    const int stride = gridDim.x * blockDim.x;
    for (int e = idx; e < N_EDGES; e += stride) {
        int i = ei[e];
        int j = ei[N_EDGES + e];
        float2 pi = pred[i];
        float2 pj = pred[j];
        float dx = pi.x - pj.x, dy = pi.y - pj.y;
        float l2 = dx * dx + dy * dy;
        s2 += l2;
        s1 += sqrtf(l2);
    }
    edge_flush(s1, s2, ws, edge_mode, smem1, smem2);
}

__global__ void finalize(const double* __restrict__ ws,
                         const int* __restrict__ epoch_p,
                         float* __restrict__ out,
                         int ns, int edge_mode) {
    double recon_sum = 0.0, kl_sum = 0.0;
    for (int s = 0; s < ns; ++s) {
        recon_sum += ws[SH_BASE + s * SH_STRIDE + 0];
        kl_sum    += ws[SH_BASE + s * SH_STRIDE + 1];
    }
    double S1, S2;
    if (edge_mode) {
        S1 = 0.0; S2 = 0.0;
        for (int s = 0; s < EDGE_NSHADOW; ++s) {
            S1 += ws[EDGE_SH_BASE + s * 8 + 0];
            S2 += ws[EDGE_SH_BASE + s * 8 + 1];
        }
    } else {
        S1 = ws[1]; S2 = ws[2];
    }
    double recon = recon_sum / (2.0 * (double)N_NODES);
    double lap  = S2 / (double)N_EDGES;
    double arap = (S2 - S1 * S1 / (double)N_EDGES) / ((double)N_EDGES - 1.0);
    double drift = 0.0;
    for (int g = 0; g < NUM_GRAPHS; ++g) {
        double c = 0.0, sx = 0.0, sy = 0.0;
        for (int s = 0; s < ns; ++s) {
            c  += ws[SH_BASE + s * SH_STRIDE + 130 + g];
            sx += ws[SH_BASE + s * SH_STRIDE + 2 + g];
            sy += ws[SH_BASE + s * SH_STRIDE + 66 + g];
        }
        double mx = sx / c, my = sy / c;
        drift += mx * mx + my * my;
    }
    drift /= (double)NUM_GRAPHS;
    double kl = -0.5 * kl_sum / (double)NUM_GRAPHS;
    int epoch = *epoch_p;
    double beta = (epoch < 10) ? ((double)epoch / 10.0) : 1.0;
    out[0] = (float)(recon + 0.1 * lap + 0.01 * drift + 0.1 * arap + beta * kl);
}

extern "C" void kernel_launch(void* const* d_in, const int* in_sizes, int n_in,
                              void* d_out, int out_size, void* d_ws, size_t ws_size,
                              hipStream_t stream) {
    const float2* pred   = (const float2*)d_in[0];
    const float2* targ   = (const float2*)d_in[1];
    const int*    ei     = (const int*)d_in[2];
    const int*    batch  = (const int*)d_in[3];
    const float*  mu     = (const float*)d_in[4];
    const float*  logvar = (const float*)d_in[5];
    const int*    epoch  = (const int*)d_in[6];
    float* out = (float*)d_out;
    double* ws = (double*)d_ws;

    const size_t packed_bytes = 4ull * N_NODES;
    int ns, edge_mode;
    unsigned* packed;
    if (ws_size >= (size_t)PACKED_OFFSET_BIG + packed_bytes) {
        ns = NSHADOW_BIG; edge_mode = 1;
        packed = (unsigned*)((char*)d_ws + PACKED_OFFSET_BIG);
    } else if (ws_size >= (size_t)PACKED_OFFSET_LEGACY + packed_bytes) {
        ns = 1; edge_mode = 0;
        packed = (unsigned*)((char*)d_ws + PACKED_OFFSET_LEGACY);
    } else {
        ns = 1; edge_mode = 0;
        packed = nullptr;
    }
    const int nz = edge_mode ? WS_DOUBLES_TOT : WS_DOUBLES_LEGACY;

    init_ws<<<(nz + 255) / 256, 256, 0, stream>>>(ws, nz);
    node_kl_pass<<<1024, 256, 0, stream>>>(pred, targ, batch, mu, logvar, ws,
                                           packed, ns);
    if (packed) {
        // 2x2 factorial, 4M edges per arm, identical hand-managed structure:
        //   A: depth8  default | B: depth8  sc0
        //   C: depth16 default | D: depth16 sc0
        const int q8  = N_EDGES / 8 / 4;   // 500000 8-edge groups / arm
        const int q16 = N_EDGES / 16 / 4;  // 250000 16-edge groups / arm
        edge_pass8<false><<<1024, 256, 0, stream>>>(packed, ei, ws, edge_mode,
                                                    0, q8);
        edge_pass8<true><<<1024, 256, 0, stream>>>(packed, ei, ws, edge_mode,
                                                   q8, q8);
        edge_pass16<false><<<1024, 256, 0, stream>>>(packed, ei, ws, edge_mode,
                                                     2 * q16, q16);
        edge_pass16<true><<<1024, 256, 0, stream>>>(packed, ei, ws, edge_mode,
                                                    3 * q16, q16);
    } else {
        edge_pass_f32<<<2048, 256, 0, stream>>>(pred, ei, ws, edge_mode);
    }
    finalize<<<1, 1, 0, stream>>>(ws, epoch, out, ns, edge_mode);
}

// Round 9
// 393.970 us; speedup vs baseline: 1.1466x; 1.1466x over previous
//
#include <hip/hip_runtime.h>
#include <hip/hip_fp16.h>
#include <math.h>

#define N_NODES    1000000
#define N_EDGES    16000000
#define NUM_GRAPHS 64
#define LATENT     128

// ws layout (doubles):
// [0..4): legacy scalars: [1] S1 [2] S2 (legacy edge mode)
// node shadow region: 8 copies at SH_BASE + s*SH_STRIDE:
//   +0 recon, +1 kl, +2..66 gx, +66..130 gy, +130..194 cnt
// edge shadows (big mode): 16 line-separated {S1,S2} pairs at EDGE_SH_BASE + sh*8
// packed half2 table at byte offset 16384 (big mode) or 2048 (legacy mode)
#define SH_BASE        8
#define SH_STRIDE      200
#define NSHADOW_BIG    8
#define EDGE_SH_BASE   1608   // 8 + 8*200
#define EDGE_NSHADOW   16
#define WS_DOUBLES_TOT 1736   // 1608 + 16*8
#define WS_DOUBLES_LEGACY 208
#define PACKED_OFFSET_BIG    16384
#define PACKED_OFFSET_LEGACY 2048

typedef int vint4 __attribute__((ext_vector_type(4)));

__global__ void init_ws(double* ws, int n) {
    int t = blockIdx.x * blockDim.x + threadIdx.x;
    if (t < n) ws[t] = 0.0;
}

// Wave-contiguous node pass: each wave owns a contiguous ~123-node chunk
// (coalesced loads; a thread's nodes lie in ONE graph almost always).
// Per-thread accumulators flush to LDS only on graph change / at end —
// replaces the measured ~70 µs of per-iteration shfl-reduce VALU burn
// (roofline for this kernel is ~4 µs of memory traffic).
__global__ void node_kl_pass(const float2* __restrict__ pred,
                             const float2* __restrict__ targ,
                             const int*    __restrict__ batch,
                             const float*  __restrict__ mu,
                             const float*  __restrict__ logvar,
                             double* __restrict__ ws,
                             unsigned* __restrict__ packed,  // may be null
                             int ns) {
    __shared__ float sgx[NUM_GRAPHS];
    __shared__ float sgy[NUM_GRAPHS];
    __shared__ int   scnt[NUM_GRAPHS];
    __shared__ double smem[8];

    for (int g = threadIdx.x; g < NUM_GRAPHS; g += blockDim.x) {
        sgx[g] = 0.f; sgy[g] = 0.f; scnt[g] = 0;
    }
    __syncthreads();

    double* shbase = ws + SH_BASE + (size_t)(blockIdx.x & (ns - 1)) * SH_STRIDE;

    const int lane   = threadIdx.x & 63;
    const int wid    = threadIdx.x >> 6;
    const int nwaves = (gridDim.x * blockDim.x) >> 6;
    const int gwave  = (blockIdx.x * blockDim.x + threadIdx.x) >> 6;
    const int chunk  = (N_NODES + nwaves - 1) / nwaves;
    const int start  = gwave * chunk;
    const int end    = (start + chunk < N_NODES) ? (start + chunk) : N_NODES;

    float recon = 0.f;
    float sx = 0.f, sy = 0.f;
    int   cnt = 0, bcur = -1;

    for (int n0 = start; n0 < end; n0 += 64) {
        const int n = n0 + lane;
        if (n < end) {
            float2 p = pred[n];
            float2 t = targ[n];
            float dx = p.x - t.x, dy = p.y - t.y;
            recon += dx * dx + dy * dy;

            if (packed) {
                __half2 h = __floats2half2_rn(p.x, p.y);
                packed[n] = *reinterpret_cast<unsigned*>(&h);
            }

            int b = batch[n];
            if (b != bcur) {
                if (cnt != 0) {
                    atomicAdd(&sgx[bcur], sx);
                    atomicAdd(&sgy[bcur], sy);
                    atomicAdd(&scnt[bcur], cnt);
                }
                bcur = b; sx = 0.f; sy = 0.f; cnt = 0;
            }
            sx += p.x; sy += p.y; ++cnt;
        }
    }
    if (cnt != 0) {
        atomicAdd(&sgx[bcur], sx);
        atomicAdd(&sgy[bcur], sy);
        atomicAdd(&scnt[bcur], cnt);
    }

    // reduce recon across block (once, not per iteration)
    double r = (double)recon;
    #pragma unroll
    for (int off = 32; off > 0; off >>= 1) r += __shfl_down(r, off);
    if (lane == 0) smem[wid] = r;
    __syncthreads();
    if (threadIdx.x == 0) {
        double tot = 0.0;
        const int nw = blockDim.x >> 6;
        for (int w = 0; w < nw; ++w) tot += smem[w];
        atomicAdd(&shbase[0], tot);
    }

    for (int g = threadIdx.x; g < NUM_GRAPHS; g += blockDim.x) {
        if (scnt[g] != 0) {
            atomicAdd(&shbase[2 + g],   (double)sgx[g]);
            atomicAdd(&shbase[66 + g],  (double)sgy[g]);
            atomicAdd(&shbase[130 + g], (double)scnt[g]);
        }
    }

    // KL tail: block 0 only (8192 elements, overlapped with other blocks)
    if (blockIdx.x == 0) {
        double s = 0.0;
        for (int t = threadIdx.x; t < NUM_GRAPHS * LATENT; t += blockDim.x) {
            float m = mu[t], lv = logvar[t];
            s += (double)(1.0f + lv - m * m - expf(lv));
        }
        #pragma unroll
        for (int off = 32; off > 0; off >>= 1) s += __shfl_down(s, off);
        __syncthreads();
        if (lane == 0) smem[wid] = s;
        __syncthreads();
        if (threadIdx.x == 0) {
            double tot = 0.0;
            const int nw = blockDim.x >> 6;
            for (int w = 0; w < nw; ++w) tot += smem[w];
            atomicAdd(&shbase[1], tot);
        }
    }
}

__device__ __forceinline__ void edge_flush(float s1, float s2, double* ws,
                                           int edge_mode,
                                           double* smem1, double* smem2) {
    double r1 = (double)s1, r2 = (double)s2;
    #pragma unroll
    for (int off = 32; off > 0; off >>= 1) {
        r1 += __shfl_down(r1, off);
        r2 += __shfl_down(r2, off);
    }
    const int lane = threadIdx.x & 63;
    const int wid  = threadIdx.x >> 6;
    if (lane == 0) { smem1[wid] = r1; smem2[wid] = r2; }
    __syncthreads();
    if (threadIdx.x == 0) {
        double t1 = 0.0, t2 = 0.0;
        const int nw = blockDim.x >> 6;
        for (int w = 0; w < nw; ++w) { t1 += smem1[w]; t2 += smem2[w]; }
        if (edge_mode) {
            // 16 line-separated shadow pairs: avoids one-line atomic chains
            const int sh = blockIdx.x & (EDGE_NSHADOW - 1);
            atomicAdd(&ws[EDGE_SH_BASE + sh * 8 + 0], t1);
            atomicAdd(&ws[EDGE_SH_BASE + sh * 8 + 1], t2);
        } else {
            atomicAdd(&ws[1], t1);
            atomicAdd(&ws[2], t2);
        }
    }
}

// ===== Edge pass: EXACT round-1 measured-170µs structure =====
// 4 edges / 8 compiler-tracked gathers per iteration; nontemporal index
// prefetch issued between gathers and consume (compiler-inserted counted
// waits keep the prefetch in flight). sc0/depth-16 variants measured null
// (round-8 factorial aggregate): the pass is L2 random-request bound.
__global__ void edge_pass_packed(const unsigned* __restrict__ packed,
                                 const int* __restrict__ ei,
                                 double* __restrict__ ws,
                                 int edge_mode) {
    __shared__ double smem1[8];
    __shared__ double smem2[8];

    float s1 = 0.f, s2 = 0.f;
    const int gid = blockIdx.x * blockDim.x + threadIdx.x;
    const int stride = gridDim.x * blockDim.x;
    const int ngroups = N_EDGES / 4;
    const vint4* eia = (const vint4*)ei;
    const vint4* eib = (const vint4*)(ei + N_EDGES);

    int g = gid;
    if (g < ngroups) {
        vint4 a = __builtin_nontemporal_load(eia + g);
        vint4 b = __builtin_nontemporal_load(eib + g);
        while (true) {
            // 1) issue the 8 gathers for the current group
            unsigned pa0 = packed[a.x], pb0 = packed[b.x];
            unsigned pa1 = packed[a.y], pb1 = packed[b.y];
            unsigned pa2 = packed[a.z], pb2 = packed[b.z];
            unsigned pa3 = packed[a.w], pb3 = packed[b.w];

            // 2) issue next iteration's index loads (prefetch)
            const int gn = g + stride;
            const bool more = gn < ngroups;
            vint4 an = {0, 0, 0, 0}, bn = {0, 0, 0, 0};
            if (more) {
                an = __builtin_nontemporal_load(eia + gn);
                bn = __builtin_nontemporal_load(eib + gn);
            }

            // 3) consume gathers (counted waits leave prefetch in flight)
            {
                __half2 ha = *reinterpret_cast<__half2*>(&pa0);
                __half2 hb = *reinterpret_cast<__half2*>(&pb0);
                float2 fa = __half22float2(ha);
                float2 fb = __half22float2(hb);
                float dx = fa.x - fb.x, dy = fa.y - fb.y;
                float l2 = dx * dx + dy * dy;
                s2 += l2; s1 += sqrtf(l2);
            }
            {
                __half2 ha = *reinterpret_cast<__half2*>(&pa1);
                __half2 hb = *reinterpret_cast<__half2*>(&pb1);
                float2 fa = __half22float2(ha);
                float2 fb = __half22float2(hb);
                float dx = fa.x - fb.x, dy = fa.y - fb.y;
                float l2 = dx * dx + dy * dy;
                s2 += l2; s1 += sqrtf(l2);
            }
            {
                __half2 ha = *reinterpret_cast<__half2*>(&pa2);
                __half2 hb = *reinterpret_cast<__half2*>(&pb2);
                float2 fa = __half22float2(ha);
                float2 fb = __half22float2(hb);
                float dx = fa.x - fb.x, dy = fa.y - fb.y;
                float l2 = dx * dx + dy * dy;
                s2 += l2; s1 += sqrtf(l2);
            }
            {
                __half2 ha = *reinterpret_cast<__half2*>(&pa3);
                __half2 hb = *reinterpret_cast<__half2*>(&pb3);
                float2 fa = __half22float2(ha);
                float2 fb = __half22float2(hb);
                float dx = fa.x - fb.x, dy = fa.y - fb.y;
                float l2 = dx * dx + dy * dy;
                s2 += l2; s1 += sqrtf(l2);
            }

            if (!more) break;
            g = gn; a = an; b = bn;
        }
    }
    edge_flush(s1, s2, ws, edge_mode, smem1, smem2);
}

// Fallback (ws too small for packed table): original float2 gathers.
__global__ void edge_pass_f32(const float2* __restrict__ pred,
                              const int* __restrict__ ei,
                              double* __restrict__ ws,
                              int edge_mode) {
    __shared__ double smem1[8];
    __shared__ double smem2[8];

    float s1 = 0.f, s2 = 0.f;
    const int idx = blockIdx.x * blockDim.x + threadIdx.x;
    const int stride = gridDim.x * blockDim.x;
    for (int e = idx; e < N_EDGES; e += stride) {
        int i = ei[e];
        int j = ei[N_EDGES + e];
        float2 pi = pred[i];
        float2 pj = pred[j];
        float dx = pi.x - pj.x, dy = pi.y - pj.y;
        float l2 = dx * dx + dy * dy;
        s2 += l2;
        s1 += sqrtf(l2);
    }
    edge_flush(s1, s2, ws, edge_mode, smem1, smem2);
}

__global__ void finalize(const double* __restrict__ ws,
                         const int* __restrict__ epoch_p,
                         float* __restrict__ out,
                         int ns, int edge_mode) {
    double recon_sum = 0.0, kl_sum = 0.0;
    for (int s = 0; s < ns; ++s) {
        recon_sum += ws[SH_BASE + s * SH_STRIDE + 0];
        kl_sum    += ws[SH_BASE + s * SH_STRIDE + 1];
    }
    double S1, S2;
    if (edge_mode) {
        S1 = 0.0; S2 = 0.0;
        for (int s = 0; s < EDGE_NSHADOW; ++s) {
            S1 += ws[EDGE_SH_BASE + s * 8 + 0];
            S2 += ws[EDGE_SH_BASE + s * 8 + 1];
        }
    } else {
        S1 = ws[1]; S2 = ws[2];
    }
    double recon = recon_sum / (2.0 * (double)N_NODES);
    double lap  = S2 / (double)N_EDGES;
    double arap = (S2 - S1 * S1 / (double)N_EDGES) / ((double)N_EDGES - 1.0);
    double drift = 0.0;
    for (int g = 0; g < NUM_GRAPHS; ++g) {
        double c = 0.0, sx = 0.0, sy = 0.0;
        for (int s = 0; s < ns; ++s) {
            c  += ws[SH_BASE + s * SH_STRIDE + 130 + g];
            sx += ws[SH_BASE + s * SH_STRIDE + 2 + g];
            sy += ws[SH_BASE + s * SH_STRIDE + 66 + g];
        }
        double mx = sx / c, my = sy / c;
        drift += mx * mx + my * my;
    }
    drift /= (double)NUM_GRAPHS;
    double kl = -0.5 * kl_sum / (double)NUM_GRAPHS;
    int epoch = *epoch_p;
    double beta = (epoch < 10) ? ((double)epoch / 10.0) : 1.0;
    out[0] = (float)(recon + 0.1 * lap + 0.01 * drift + 0.1 * arap + beta * kl);
}

extern "C" void kernel_launch(void* const* d_in, const int* in_sizes, int n_in,
                              void* d_out, int out_size, void* d_ws, size_t ws_size,
                              hipStream_t stream) {
    const float2* pred   = (const float2*)d_in[0];
    const float2* targ   = (const float2*)d_in[1];
    const int*    ei     = (const int*)d_in[2];
    const int*    batch  = (const int*)d_in[3];
    const float*  mu     = (const float*)d_in[4];
    const float*  logvar = (const float*)d_in[5];
    const int*    epoch  = (const int*)d_in[6];
    float* out = (float*)d_out;
    double* ws = (double*)d_ws;

    const size_t packed_bytes = 4ull * N_NODES;
    int ns, edge_mode;
    unsigned* packed;
    if (ws_size >= (size_t)PACKED_OFFSET_BIG + packed_bytes) {
        ns = NSHADOW_BIG; edge_mode = 1;
        packed = (unsigned*)((char*)d_ws + PACKED_OFFSET_BIG);
    } else if (ws_size >= (size_t)PACKED_OFFSET_LEGACY + packed_bytes) {
        ns = 1; edge_mode = 0;
        packed = (unsigned*)((char*)d_ws + PACKED_OFFSET_LEGACY);
    } else {
        ns = 1; edge_mode = 0;
        packed = nullptr;
    }
    const int nz = edge_mode ? WS_DOUBLES_TOT : WS_DOUBLES_LEGACY;

    init_ws<<<(nz + 255) / 256, 256, 0, stream>>>(ws, nz);
    node_kl_pass<<<2048, 256, 0, stream>>>(pred, targ, batch, mu, logvar, ws,
                                           packed, ns);
    if (packed)
        edge_pass_packed<<<2048, 256, 0, stream>>>(packed, ei, ws, edge_mode);
    else
        edge_pass_f32<<<2048, 256, 0, stream>>>(pred, ei, ws, edge_mode);
    finalize<<<1, 1, 0, stream>>>(ws, epoch, out, ns, edge_mode);
}